// Round 9
// baseline (283.931 us; speedup 1.0000x reference)
//
#include <hip/hip_runtime.h>
#include <hip/hip_bf16.h>
#include <math.h>

// Problem constants
#define S_LEN 2048
#define BATCH 4
#define HID   1024
#define HEADS 16
#define HD    64
#define SB    (S_LEN*BATCH)       // 8192 rows
#define CHUNK 64
#define NCHUNK (S_LEN/CHUNK)      // 32
#define BH    (BATCH*HEADS)       // 64
#define NSTK  3200                // 1024*3 (QKV) + 16 (F) padded to 25*128

typedef __bf16 bf16x8 __attribute__((ext_vector_type(8)));
typedef float  f32x4  __attribute__((ext_vector_type(4)));
typedef unsigned short ushort_t;
typedef unsigned short u16x8 __attribute__((ext_vector_type(8)));
typedef unsigned short u16x4 __attribute__((ext_vector_type(4)));

__device__ __forceinline__ unsigned short f2bf(float x) {
    union { float f; unsigned int u; } un; un.f = x;
    unsigned int u = un.u;
    unsigned int r = (u + 0x7FFFu + ((u >> 16) & 1u)) >> 16;  // RNE
    return (unsigned short)r;
}
__device__ __forceinline__ float bf2f(unsigned short s) {
    union { unsigned int u; float f; } un; un.u = ((unsigned int)s) << 16;
    return un.f;
}

// XOR j-block swizzle for [64][72] LDS tiles: spreads strided scatter
// writes across banks; 8-element-contiguous reads stay 16B-aligned.
#define JSW(row, j) ((j) ^ ((((row) >> 3) & 7) << 3))

#define GLL16(src, dst) __builtin_amdgcn_global_load_lds( \
    (const __attribute__((address_space(1))) void*)(src), \
    (__attribute__((address_space(3))) void*)(dst), 16, 0, 0)

// ---------------------------------------------------------------------------
// Prep kernel (one dispatch): X->bf16; Wstk build; Wo->bf16; bstk build.
// ---------------------------------------------------------------------------
#define NXU (SB*HID/4)          // 2097152
#define NW1 (NSTK*HID/4)        // 819200
#define NW2 (HID*HID/4)         // 262144
#define NBU (NSTK/4)            // 800
#define NTOT (NXU+NW1+NW2+NBU)

__global__ __launch_bounds__(256) void prep_kernel(
    const float* __restrict__ X,  const float* __restrict__ Wq,
    const float* __restrict__ Wk, const float* __restrict__ Wv,
    const float* __restrict__ Wf, const float* __restrict__ Wo,
    const float* __restrict__ bq, const float* __restrict__ bk,
    const float* __restrict__ bv, const float* __restrict__ bf,
    ushort_t* __restrict__ Xb, ushort_t* __restrict__ Wstk,
    ushort_t* __restrict__ Wob, float* __restrict__ bstk)
{
    const int i = blockIdx.x * 256 + threadIdx.x;
    if (i < NXU) {
        float4 v = ((const float4*)X)[i];
        ushort4 o; o.x=f2bf(v.x); o.y=f2bf(v.y); o.z=f2bf(v.z); o.w=f2bf(v.w);
        ((ushort4*)Xb)[i] = o;
    } else if (i < NXU + NW1) {
        const int idx4 = (i - NXU) * 4;
        const int row = idx4 >> 10, col = idx4 & 1023;
        float4 v;
        if      (row < 1024) v = *(const float4*)(Wq + (size_t)row*HID + col);
        else if (row < 2048) v = *(const float4*)(Wk + (size_t)(row-1024)*HID + col);
        else if (row < 3072) v = *(const float4*)(Wv + (size_t)(row-2048)*HID + col);
        else if (row < 3088) v = *(const float4*)(Wf + (size_t)(row-3072)*HID + col);
        else                 v = make_float4(0.f,0.f,0.f,0.f);
        ushort4 o; o.x=f2bf(v.x); o.y=f2bf(v.y); o.z=f2bf(v.z); o.w=f2bf(v.w);
        *(ushort4*)(Wstk + idx4) = o;
    } else if (i < NXU + NW1 + NW2) {
        const int idx4 = (i - NXU - NW1) * 4;
        float4 v = *(const float4*)(Wo + idx4);
        ushort4 o; o.x=f2bf(v.x); o.y=f2bf(v.y); o.z=f2bf(v.z); o.w=f2bf(v.w);
        *(ushort4*)(Wob + idx4) = o;
    } else if (i < NTOT) {
        const int idx4 = (i - NXU - NW1 - NW2) * 4;
        #pragma unroll
        for (int t = 0; t < 4; ++t) {
            const int c = idx4 + t;
            float v;
            if      (c < 1024) v = bq[c];
            else if (c < 2048) v = bk[c-1024];
            else if (c < 3072) v = bv[c-2048];
            else if (c < 3088) v = bf[c-3072];
            else               v = 0.f;
            bstk[c] = v;
        }
    }
}

// ---------------------------------------------------------------------------
// Fused QKV+F GEMM (16x16x32 MFMA) — verified structure (round-0/3/6/8).
// Grid: x = ROW panel (64), y = COL panel (25).
// ---------------------------------------------------------------------------
__global__ __launch_bounds__(256) void qkvf_gemm(
    const ushort_t* __restrict__ X, const ushort_t* __restrict__ W,
    const float* __restrict__ bias,
    ushort_t* __restrict__ Q, ushort_t* __restrict__ Kr,
    ushort_t* __restrict__ V,
    float* __restrict__ f_out, float* __restrict__ logf_out)
{
    __shared__ ushort_t As[128 * 32];
    __shared__ ushort_t Bs[128 * 32];

    const int tid  = threadIdx.x;
    const int wave = tid >> 6, lane = tid & 63;
    const int waveM = wave >> 1, waveN = wave & 1;
    const int rowBase = blockIdx.x * 128;
    const int colBase = blockIdx.y * 128;
    const int K = HID;

    f32x4 acc[4][4];
    #pragma unroll
    for (int i = 0; i < 4; ++i)
        #pragma unroll
        for (int j = 0; j < 4; ++j)
            acc[i][j] = (f32x4){0.f, 0.f, 0.f, 0.f};

    const int srow = lane >> 2;
    const int scol = (lane & 3) * 8;

    const ushort_t* gA0 = X + (size_t)(rowBase + wave*16 + srow) * K + scol;
    const ushort_t* gB0 = W + (size_t)(colBase + wave*16 + srow) * K + scol;
    ushort_t* lA = As + (wave*16)*32;
    ushort_t* lB = Bs + (wave*16)*32;

    const int fr = lane & 15;
    const int fk = (lane >> 4) * 8;

    for (int k0 = 0; k0 < K; k0 += 32) {
        GLL16(gA0 + k0,                lA);
        GLL16(gA0 + (size_t)64*K + k0, lA + 64*32);
        GLL16(gB0 + k0,                lB);
        GLL16(gB0 + (size_t)64*K + k0, lB + 64*32);

        __syncthreads();

        bf16x8 a[4], b[4];
        #pragma unroll
        for (int i = 0; i < 4; ++i)
            a[i] = *(const bf16x8*)(As + (waveM*64 + i*16 + fr)*32 + fk);
        #pragma unroll
        for (int j = 0; j < 4; ++j)
            b[j] = *(const bf16x8*)(Bs + (waveN*64 + j*16 + fr)*32 + fk);

        #pragma unroll
        for (int i = 0; i < 4; ++i)
            #pragma unroll
            for (int j = 0; j < 4; ++j)
                acc[i][j] = __builtin_amdgcn_mfma_f32_16x16x32_bf16(
                    a[i], b[j], acc[i][j], 0, 0, 0);

        __syncthreads();
    }

    const int er = (lane >> 4) * 4;
    const int ec = lane & 15;
    #pragma unroll
    for (int i = 0; i < 4; ++i) {
        #pragma unroll
        for (int j = 0; j < 4; ++j) {
            const int r0 = rowBase + waveM*64 + i*16 + er;
            const int c0 = colBase + waveN*64 + j*16;        // lane-uniform
            if (c0 >= 3088) continue;
            const int c  = c0 + ec;
            const float bv = bias[c];
            #pragma unroll
            for (int k = 0; k < 4; ++k) {
                float v = acc[i][j][k] + bv;
                const int r = r0 + k;
                if (c0 < 1024) {
                    v = (v > 0.f) ? (v + 1.f) : __expf(v);
                    Q[(size_t)r * HID + c] = f2bf(v);
                } else if (c0 < 2048) {
                    v = (v > 0.f) ? (v + 1.f) : __expf(v);
                    Kr[(size_t)r * HID + (c - 1024)] = f2bf(v);
                } else if (c0 < 3072) {
                    V[(size_t)r * HID + (c - 2048)] = f2bf(v);
                } else {
                    const int n = c - 3072;
                    const float fv = 1.f / (1.f + __expf(-v));
                    f_out[(size_t)r * HEADS + n]    = fv;
                    logf_out[(size_t)r * HEADS + n] = -__logf(1.f + __expf(-v));
                }
            }
        }
    }
}

// ---------------------------------------------------------------------------
// Output GEMM: out = AO @ Wo^T + bo (fp32) — verified structure.
// Zero-fill of slot 1 via hipMemsetAsync in launcher.
// ---------------------------------------------------------------------------
__global__ __launch_bounds__(256) void gemm_out(
    const ushort_t* __restrict__ X, const ushort_t* __restrict__ W,
    const float* __restrict__ bias, float* __restrict__ Y)
{
    __shared__ ushort_t As[128 * 32];
    __shared__ ushort_t Bs[128 * 32];

    const int tid  = threadIdx.x;
    const int wave = tid >> 6, lane = tid & 63;
    const int waveM = wave >> 1, waveN = wave & 1;
    const int rowBase = blockIdx.x * 128;
    const int colBase = blockIdx.y * 128;
    const int K = HID, N = HID;

    f32x4 acc[4][4];
    #pragma unroll
    for (int i = 0; i < 4; ++i)
        #pragma unroll
        for (int j = 0; j < 4; ++j)
            acc[i][j] = (f32x4){0.f, 0.f, 0.f, 0.f};

    const int srow = lane >> 2;
    const int scol = (lane & 3) * 8;

    const ushort_t* gA0 = X + (size_t)(rowBase + wave*16 + srow) * K + scol;
    const ushort_t* gB0 = W + (size_t)(colBase + wave*16 + srow) * K + scol;
    ushort_t* lA = As + (wave*16)*32;
    ushort_t* lB = Bs + (wave*16)*32;

    const int fr = lane & 15;
    const int fk = (lane >> 4) * 8;

    for (int k0 = 0; k0 < K; k0 += 32) {
        GLL16(gA0 + k0,                lA);
        GLL16(gA0 + (size_t)64*K + k0, lA + 64*32);
        GLL16(gB0 + k0,                lB);
        GLL16(gB0 + (size_t)64*K + k0, lB + 64*32);

        __syncthreads();

        bf16x8 a[4], b[4];
        #pragma unroll
        for (int i = 0; i < 4; ++i)
            a[i] = *(const bf16x8*)(As + (waveM*64 + i*16 + fr)*32 + fk);
        #pragma unroll
        for (int j = 0; j < 4; ++j)
            b[j] = *(const bf16x8*)(Bs + (waveN*64 + j*16 + fr)*32 + fk);

        #pragma unroll
        for (int i = 0; i < 4; ++i)
            #pragma unroll
            for (int j = 0; j < 4; ++j)
                acc[i][j] = __builtin_amdgcn_mfma_f32_16x16x32_bf16(
                    a[i], b[j], acc[i][j], 0, 0, 0);

        __syncthreads();
    }

    const int er = (lane >> 4) * 4;
    const int ec = lane & 15;
    #pragma unroll
    for (int i = 0; i < 4; ++i) {
        #pragma unroll
        for (int j = 0; j < 4; ++j) {
            const int r0 = rowBase + waveM*64 + i*16 + er;
            const int c  = colBase + waveN*64 + j*16 + ec;
            const float bv = bias[c];
            #pragma unroll
            for (int k = 0; k < 4; ++k) {
                const size_t off = (size_t)(r0 + k) * N + c;
                Y[off] = acc[i][j][k] + bv;
            }
        }
    }
}

// ---------------------------------------------------------------------------
// Pass 1 (MFMA): ScT[e][d] = sum_j v[j][e]*(exd_j k[j][d]); z[d] likewise.
// JSW-swizzled transposed LDS tiles; Schunk output now transposed through
// LDS (vsT region, dead after main MFMAs) -> 2 coalesced u16x8 stores/thread
// instead of 16 scattered 2B stores.
// ---------------------------------------------------------------------------
__global__ __launch_bounds__(256) void pass1_kernel(
    const ushort_t* __restrict__ Kp, const ushort_t* __restrict__ Vp,
    const float* __restrict__ logf,
    ushort_t* __restrict__ Schunk, float* __restrict__ zchunk,
    float* __restrict__ Dchunk)
{
    __shared__ __align__(16) char smem[18688];
    ushort_t* vsT = (ushort_t*)smem;            // [64][72]: row e, col j (JSW); reused for out
    ushort_t* kTd = (ushort_t*)(smem + 9216);   // [64][72]: row d, col j (JSW)
    float*    exd = (float*)(smem + 18432);     // [64]

    const int chunk = blockIdx.x;
    const int bh = blockIdx.y;
    const int b = bh >> 4, h = bh & 15;
    const int tid = threadIdx.x;
    const int wv = tid >> 6, ln = tid & 63;
    const int fr = ln & 15, q4 = ln >> 4;
    const size_t slot = (size_t)bh * NCHUNK + chunk;

    u16x8 vreg[2], kreg[2];
    #pragma unroll
    for (int it = 0; it < 2; ++it) {
        const int u = it*256 + tid;
        const int j = u >> 3, d8 = (u & 7) * 8;
        const size_t base = (size_t)((chunk*64 + j)*BATCH + b)*HID + h*HD + d8;
        vreg[it] = *(const u16x8*)(Vp + base);
        kreg[it] = *(const u16x8*)(Kp + base);
    }
    if (tid < 64) {
        float v = logf[(size_t)((chunk*64 + tid)*BATCH + b) * HEADS + h];
        #pragma unroll
        for (int off = 1; off < 64; off <<= 1) {
            float n = __shfl_up(v, off);
            if (tid >= off) v += n;
        }
        const float tot = __shfl(v, 63);
        exd[tid] = __expf(tot - v);
        if (tid == 63) Dchunk[slot] = __expf(tot);
    }
    __syncthreads();

    #pragma unroll
    for (int it = 0; it < 2; ++it) {
        const int u = it*256 + tid;
        const int j = u >> 3, d8 = (u & 7) * 8;
        const int js = j ^ ((u & 7) << 3);       // JSW(d8+i, j), (d8+i)>>3 == u&7
        const float ex = exd[j];
        #pragma unroll
        for (int i = 0; i < 8; ++i) {
            vsT[(d8+i)*72 + js] = vreg[it][i];
            kTd[(d8+i)*72 + js] = f2bf(bf2f(kreg[it][i]) * ex);
        }
    }
    __syncthreads();

    f32x4 acc[4];
    #pragma unroll
    for (int nt = 0; nt < 4; ++nt) acc[nt] = (f32x4){0.f,0.f,0.f,0.f};
    #pragma unroll
    for (int k0 = 0; k0 < 64; k0 += 32) {
        const int rA = wv*16 + fr;
        bf16x8 av = *(const bf16x8*)(vsT + rA*72 + JSW(rA, k0 + q4*8));
        #pragma unroll
        for (int nt = 0; nt < 4; ++nt) {
            const int rB = nt*16 + fr;
            bf16x8 bk = *(const bf16x8*)(kTd + rB*72 + JSW(rB, k0 + q4*8));
            acc[nt] = __builtin_amdgcn_mfma_f32_16x16x32_bf16(av, bk, acc[nt], 0, 0, 0);
        }
    }

    __syncthreads();   // all vsT fragment reads complete -> region reusable

    // stage transposed output [e][col] (JSW) into vsT region
    #pragma unroll
    for (int nt = 0; nt < 4; ++nt) {
        #pragma unroll
        for (int r = 0; r < 4; ++r) {
            const int e = wv*16 + q4*4 + r;
            const int col = nt*16 + fr;
            vsT[e*72 + JSW(e, col)] = f2bf(acc[nt][r]);
        }
    }

    if (wv == 0) {     // z-loop: kTd untouched by staging; overlaps others' writes
        u16x8 onesu;
        #pragma unroll
        for (int i = 0; i < 8; ++i) onesu[i] = 0x3F80;   // bf16 1.0
        const bf16x8 ones = *(const bf16x8*)&onesu;
        f32x4 zacc[4];
        #pragma unroll
        for (int nt = 0; nt < 4; ++nt) zacc[nt] = (f32x4){0.f,0.f,0.f,0.f};
        #pragma unroll
        for (int k0 = 0; k0 < 64; k0 += 32) {
            #pragma unroll
            for (int nt = 0; nt < 4; ++nt) {
                const int rB = nt*16 + fr;
                bf16x8 bk = *(const bf16x8*)(kTd + rB*72 + JSW(rB, k0 + q4*8));
                zacc[nt] = __builtin_amdgcn_mfma_f32_16x16x32_bf16(ones, bk, zacc[nt], 0, 0, 0);
            }
        }
        if (q4 == 0) {
            #pragma unroll
            for (int nt = 0; nt < 4; ++nt)
                zchunk[slot*64 + nt*16 + fr] = zacc[nt][0];
        }
    }
    __syncthreads();

    // coalesced store: 2 x u16x8 per thread, full 128B lines
    ushort_t* sp = Schunk + slot * 4096;
    #pragma unroll
    for (int it = 0; it < 2; ++it) {
        const int u = it*256 + tid;
        const int e = u >> 3, c8 = (u & 7) * 8;
        *(u16x8*)(sp + e*64 + c8) = *(const u16x8*)(vsT + e*72 + JSW(e, c8));
    }
}

// ---------------------------------------------------------------------------
// Pass 2: sequential over 32 chunks; 512 blocks (8 slices per bh), 128 thr,
// 4 bf16/thread via u16x4 (8B/lane), depth-2 prefetch.
// ---------------------------------------------------------------------------
__global__ __launch_bounds__(128) void pass2_kernel(
    ushort_t* __restrict__ Schunk, float* __restrict__ zchunk,
    const float* __restrict__ Dchunk)
{
    __shared__ float Ds[NCHUNK];
    const int bh  = blockIdx.x >> 3;
    const int sl  = blockIdx.x & 7;
    const int tid = threadIdx.x;

    if (tid < NCHUNK) Ds[tid] = Dchunk[bh * NCHUNK + tid];

    float Sprev[4] = {0.f, 0.f, 0.f, 0.f};
    float zprev = 0.f;

    const size_t base  = (size_t)bh * NCHUNK * 4096 + sl * 512 + tid * 4;
    const size_t zbase = (size_t)bh * NCHUNK * 64;
    const bool doZ = (sl == 0) && (tid < 64);

    u16x4 b0 = *(const u16x4*)(Schunk + base);
    u16x4 b1 = *(const u16x4*)(Schunk + base + 4096);
    float z0v = 0.f, z1v = 0.f;
    if (doZ) {
        z0v = zchunk[zbase + tid];
        z1v = zchunk[zbase + 64 + tid];
    }
    __syncthreads();

    for (int c = 0; c < NCHUNK; ++c) {
        const float D = Ds[c];
        ushort_t* sp = Schunk + base + (size_t)c * 4096;
        u16x4 wout;
        #pragma unroll
        for (int i = 0; i < 4; ++i) {
            wout[i] = f2bf(Sprev[i]);
            Sprev[i] = D * Sprev[i] + bf2f(b0[i]);
        }
        *(u16x4*)sp = wout;
        b0 = b1;
        if (doZ) {
            zchunk[zbase + (size_t)c * 64 + tid] = zprev;
            zprev = D * zprev + z0v;
            z0v = z1v;
        }
        if (c + 2 < NCHUNK) {
            b1 = *(const u16x4*)(Schunk + base + (size_t)(c+2)*4096);
            if (doZ) z1v = zchunk[zbase + (size_t)(c+2)*64 + tid];
        }
    }
}

// ---------------------------------------------------------------------------
// Pass 3 (full-MFMA): per (bh, chunk) attention outputs -> bf16 AO.
// S0 B-frags prefetched to registers at entry (round-8 win). AO output now
// transposed through LDS (psA region, dead after final MFMAs) -> 2 coalesced
// u16x8 stores/thread instead of 16 scattered 2B stores.
// ---------------------------------------------------------------------------
__global__ __launch_bounds__(256) void pass3_kernel(
    const ushort_t* __restrict__ Qp, const ushort_t* __restrict__ Kp,
    const ushort_t* __restrict__ Vp, const float* __restrict__ logf,
    const ushort_t* __restrict__ S0, const float* __restrict__ z0,
    ushort_t* __restrict__ AO)
{
    __shared__ __align__(16) char smem[28928];
    ushort_t* qs  = (ushort_t*)smem;               // [64][72] (t rows)
    ushort_t* ks  = (ushort_t*)(smem + 9216);      // [64][72] (j rows) phase A
    ushort_t* vsT = (ushort_t*)(smem + 9216);      // [64][72] (e rows, JSW) phase B
    ushort_t* psA = (ushort_t*)(smem + 18432);     // [64][72] P; reused for out
    float* cc  = (float*)(smem + 27648);
    float* exT = (float*)(smem + 27904);
    float* qz  = (float*)(smem + 28160);
    float* den = (float*)(smem + 28416);
    float* zz  = (float*)(smem + 28672);

    const int chunk = blockIdx.x;
    const int bh = blockIdx.y;
    const int b = bh >> 4, h = bh & 15;
    const int tid = threadIdx.x;
    const int wv = tid >> 6, ln = tid & 63;
    const int fr = ln & 15, q4 = ln >> 4;
    const size_t slot = (size_t)bh * NCHUNK + chunk;

    // prefetch V rows into registers (scattered to LDS after B2)
    u16x8 vreg[2];
    #pragma unroll
    for (int it = 0; it < 2; ++it) {
        const int u = it*256 + tid;
        const int j = u >> 3, d8 = (u & 7) * 8;
        vreg[it] = *(const u16x8*)(Vp + (size_t)((chunk*64 + j)*BATCH + b)*HID + h*HD + d8);
    }
    // prefetch S0 B-fragments into registers (consumed after B3)
    bf16x8 s0r[4][2];
    {
        const ushort_t* S0p = S0 + slot * 4096;
        #pragma unroll
        for (int nt = 0; nt < 4; ++nt)
            #pragma unroll
            for (int kk = 0; kk < 2; ++kk)
                s0r[nt][kk] = *(const bf16x8*)(S0p + (nt*16 + fr)*64 + kk*32 + q4*8);
    }

    if (tid < 64) {
        zz[tid] = z0[slot * 64 + tid];
        float v = logf[(size_t)((chunk*64 + tid)*BATCH + b) * HEADS + h];
        #pragma unroll
        for (int off = 1; off < 64; off <<= 1) {
            float n = __shfl_up(v, off);
            if (tid >= off) v += n;
        }
        cc[tid]  = v;
        exT[tid] = __expf(v);
    }
    #pragma unroll
    for (int it = 0; it < 2; ++it) {
        const int u = it*256 + tid;
        const int r = u >> 3, c8 = (u & 7) * 8;
        const size_t goff = (size_t)((chunk*64 + r)*BATCH + b) * HID + h*HD + c8;
        *(u16x8*)(qs + r*72 + c8) = *(const u16x8*)(Qp + goff);
        *(u16x8*)(ks + r*72 + c8) = *(const u16x8*)(Kp + goff);
    }
    __syncthreads();   // B1

    f32x4 pacc[4];
    #pragma unroll
    for (int nt = 0; nt < 4; ++nt) pacc[nt] = (f32x4){0.f,0.f,0.f,0.f};
    #pragma unroll
    for (int k0 = 0; k0 < 64; k0 += 32) {
        bf16x8 af = *(const bf16x8*)(qs + (wv*16 + fr)*72 + k0 + q4*8);
        #pragma unroll
        for (int nt = 0; nt < 4; ++nt) {
            bf16x8 bfr = *(const bf16x8*)(ks + (nt*16 + fr)*72 + k0 + q4*8);
            pacc[nt] = __builtin_amdgcn_mfma_f32_16x16x32_bf16(af, bfr, pacc[nt], 0, 0, 0);
        }
    }
    // qz[t], t = wv*16+fr, all waves: 16-elem partials over d + xor-reduce
    {
        const int t = wv*16 + fr;
        const int d0 = q4 * 16;
        float s = 0.f;
        #pragma unroll
        for (int i = 0; i < 16; ++i)
            s += bf2f(qs[t*72 + d0 + i]) * zz[d0 + i];
        s += __shfl_xor(s, 16);
        s += __shfl_xor(s, 32);
        if (q4 == 0) qz[t] = s;
    }
    __syncthreads();   // B2 — ks reads done; vsT may overwrite

    #pragma unroll
    for (int it = 0; it < 2; ++it) {
        const int u = it*256 + tid;
        const int j = u >> 3, d8 = (u & 7) * 8;
        const int js = j ^ ((u & 7) << 3);       // JSW(d8+i, j)
        #pragma unroll
        for (int i = 0; i < 8; ++i)
            vsT[(d8+i)*72 + js] = vreg[it][i];
    }
    {
        float rs[4] = {0.f, 0.f, 0.f, 0.f};
        float cct[4];
        #pragma unroll
        for (int r = 0; r < 4; ++r) cct[r] = cc[wv*16 + q4*4 + r];
        #pragma unroll
        for (int nt = 0; nt < 4; ++nt) {
            const int j = nt*16 + fr;
            const float ccj = cc[j];
            #pragma unroll
            for (int r = 0; r < 4; ++r) {
                const int t = wv*16 + q4*4 + r;
                float p = (j <= t) ? pacc[nt][r] * __expf(cct[r] - ccj) : 0.f;
                rs[r] += p;
                psA[t*72 + j] = f2bf(p);
            }
        }
        #pragma unroll
        for (int m = 1; m < 16; m <<= 1) {
            #pragma unroll
            for (int r = 0; r < 4; ++r) rs[r] += __shfl_xor(rs[r], m);
        }
        if (fr == 0) {
            #pragma unroll
            for (int r = 0; r < 4; ++r) {
                const int t = wv*16 + q4*4 + r;
                den[t] = rs[r] + exT[t] * qz[t] + 1e-6f;
            }
        }
    }
    __syncthreads();   // B3

    f32x4 oacc[4], oacc2[4];
    #pragma unroll
    for (int nt = 0; nt < 4; ++nt) {
        oacc[nt]  = (f32x4){0.f,0.f,0.f,0.f};
        oacc2[nt] = (f32x4){0.f,0.f,0.f,0.f};
    }
    #pragma unroll
    for (int kk = 0; kk < 2; ++kk) {
        const int k8 = kk*32 + q4*8;
        bf16x8 ap = *(const bf16x8*)(psA + (wv*16 + fr)*72 + k8);
        bf16x8 aq = *(const bf16x8*)(qs  + (wv*16 + fr)*72 + k8);
        #pragma unroll
        for (int nt = 0; nt < 4; ++nt) {
            const int rV = nt*16 + fr;
            bf16x8 bv = *(const bf16x8*)(vsT + rV*72 + JSW(rV, k8));
            oacc[nt] = __builtin_amdgcn_mfma_f32_16x16x32_bf16(ap, bv, oacc[nt], 0, 0, 0);
            oacc2[nt] = __builtin_amdgcn_mfma_f32_16x16x32_bf16(aq, s0r[nt][kk], oacc2[nt], 0, 0, 0);
        }
    }

    // finish outputs in registers (reads exT/den, not psA)
    unsigned short vout[4][4];
    #pragma unroll
    for (int nt = 0; nt < 4; ++nt) {
        #pragma unroll
        for (int r = 0; r < 4; ++r) {
            const int t = wv*16 + q4*4 + r;
            vout[nt][r] = f2bf((oacc[nt][r] + exT[t] * oacc2[nt][r]) / den[t]);
        }
    }
    __syncthreads();   // B4 — psA (ap) reads complete -> region reusable

    // stage transposed [t][e] (JSW) into psA region
    #pragma unroll
    for (int nt = 0; nt < 4; ++nt) {
        const int e = nt*16 + fr;
        #pragma unroll
        for (int r = 0; r < 4; ++r) {
            const int t = wv*16 + q4*4 + r;
            psA[t*72 + JSW(t, e)] = vout[nt][r];
        }
    }
    __syncthreads();   // B5

    // coalesced store: 2 x u16x8 per thread, full 128B lines
    #pragma unroll
    for (int it = 0; it < 2; ++it) {
        const int u = it*256 + tid;
        const int t = u >> 3, e8 = (u & 7) * 8;
        *(u16x8*)(AO + (size_t)((chunk*64 + t)*BATCH + b) * HID + h*HD + e8) =
            *(const u16x8*)(psA + t*72 + JSW(t, e8));
    }
}

// ---------------------------------------------------------------------------
extern "C" void kernel_launch(void* const* d_in, const int* in_sizes, int n_in,
                              void* d_out, int out_size, void* d_ws, size_t ws_size,
                              hipStream_t stream) {
    const float* X  = (const float*)d_in[0];
    const float* Wq = (const float*)d_in[1];
    const float* bq = (const float*)d_in[2];
    const float* Wk = (const float*)d_in[3];
    const float* bk = (const float*)d_in[4];
    const float* Wv = (const float*)d_in[5];
    const float* bv = (const float*)d_in[6];
    const float* Wf = (const float*)d_in[7];
    const float* bf = (const float*)d_in[8];
    const float* Wo = (const float*)d_in[9];
    const float* bo = (const float*)d_in[10];

    float* out = (float*)d_out;
    const size_t OUT_SLOT = (size_t)SB * HID;

    char* ws = (char*)d_ws;
    ushort_t* wsXb   = (ushort_t*)ws;                       // SB*HID bf16 (X, later AO)
    ushort_t* wsWstk = wsXb + (size_t)SB * HID;             // NSTK*HID bf16
    ushort_t* wsWob  = wsWstk + (size_t)NSTK * HID;         // HID*HID bf16
    ushort_t* wsQ    = wsWob + (size_t)HID * HID;           // [row][col]
    ushort_t* wsK    = wsQ + (size_t)SB * HID;              // [row][col]
    ushort_t* wsV    = wsK + (size_t)SB * HID;              // [row][col]
    float* wsBstk = (float*)(wsV + (size_t)SB * HID);       // NSTK fp32
    float* wsLogf = wsBstk + NSTK;                          // SB*HEADS fp32
    ushort_t* wsS  = (ushort_t*)(wsLogf + (size_t)SB * HEADS); // bf16 S^T chunks -> S0^T
    float* wsZ    = (float*)(wsS + (size_t)BH * NCHUNK * HD * HD);
    float* wsD    = wsZ + (size_t)BH * NCHUNK * HD;

    // zero slot 1 (second output) via memset node
    hipMemsetAsync(out + OUT_SLOT, 0, OUT_SLOT * sizeof(float), stream);

    prep_kernel<<<(NTOT + 255)/256, 256, 0, stream>>>(
        X, Wq, Wk, Wv, Wf, Wo, bq, bk, bv, bf,
        wsXb, wsWstk, wsWob, wsBstk);

    dim3 qgrid(SB/128, NSTK/128);   // x = row (64), y = col (25)
    qkvf_gemm<<<qgrid, 256, 0, stream>>>(
        wsXb, wsWstk, wsBstk, wsQ, wsK, wsV,
        out + 2*OUT_SLOT, wsLogf);

    dim3 sgrid(NCHUNK, BH);
    pass1_kernel<<<sgrid, 256, 0, stream>>>(wsK, wsV, wsLogf, wsS, wsZ, wsD);
    pass2_kernel<<<BH*8, 128, 0, stream>>>(wsS, wsZ, wsD);
    pass3_kernel<<<sgrid, 256, 0, stream>>>(wsQ, wsK, wsV, wsLogf, wsS, wsZ, wsXb);

    dim3 ogrid(SB/128, HID/128);    // x = row (64), y = col (8)
    gemm_out<<<ogrid, 256, 0, stream>>>(wsXb, wsWob, bo, out);
}

// Round 10
// 280.189 us; speedup vs baseline: 1.0134x; 1.0134x over previous
//
#include <hip/hip_runtime.h>
#include <hip/hip_bf16.h>
#include <math.h>

// Problem constants
#define S_LEN 2048
#define BATCH 4
#define HID   1024
#define HEADS 16
#define HD    64
#define SB    (S_LEN*BATCH)       // 8192 rows
#define CHUNK 64
#define NCHUNK (S_LEN/CHUNK)      // 32
#define BH    (BATCH*HEADS)       // 64
#define NSTK  3200                // 1024*3 (QKV) + 16 (F) padded to 25*128

typedef __bf16 bf16x8 __attribute__((ext_vector_type(8)));
typedef float  f32x4  __attribute__((ext_vector_type(4)));
typedef unsigned short ushort_t;
typedef unsigned short u16x8 __attribute__((ext_vector_type(8)));
typedef unsigned short u16x4 __attribute__((ext_vector_type(4)));

__device__ __forceinline__ unsigned short f2bf(float x) {
    union { float f; unsigned int u; } un; un.f = x;
    unsigned int u = un.u;
    unsigned int r = (u + 0x7FFFu + ((u >> 16) & 1u)) >> 16;  // RNE
    return (unsigned short)r;
}
__device__ __forceinline__ float bf2f(unsigned short s) {
    union { unsigned int u; float f; } un; un.u = ((unsigned int)s) << 16;
    return un.f;
}

// XOR j-block swizzle for [64][72] transposed LDS tiles: spreads the
// 8-row-stride scatter writes across all banks; reads stay 16B-contiguous.
#define JSW(row, j) ((j) ^ ((((row) >> 3) & 7) << 3))

#define GLL16(src, dst) __builtin_amdgcn_global_load_lds( \
    (const __attribute__((address_space(1))) void*)(src), \
    (__attribute__((address_space(3))) void*)(dst), 16, 0, 0)

// ---------------------------------------------------------------------------
// Prep kernel (one dispatch): X->bf16; Wstk build; Wo->bf16; bstk build.
// ---------------------------------------------------------------------------
#define NXU (SB*HID/4)          // 2097152
#define NW1 (NSTK*HID/4)        // 819200
#define NW2 (HID*HID/4)         // 262144
#define NBU (NSTK/4)            // 800
#define NTOT (NXU+NW1+NW2+NBU)

__global__ __launch_bounds__(256) void prep_kernel(
    const float* __restrict__ X,  const float* __restrict__ Wq,
    const float* __restrict__ Wk, const float* __restrict__ Wv,
    const float* __restrict__ Wf, const float* __restrict__ Wo,
    const float* __restrict__ bq, const float* __restrict__ bk,
    const float* __restrict__ bv, const float* __restrict__ bf,
    ushort_t* __restrict__ Xb, ushort_t* __restrict__ Wstk,
    ushort_t* __restrict__ Wob, float* __restrict__ bstk)
{
    const int i = blockIdx.x * 256 + threadIdx.x;
    if (i < NXU) {
        float4 v = ((const float4*)X)[i];
        ushort4 o; o.x=f2bf(v.x); o.y=f2bf(v.y); o.z=f2bf(v.z); o.w=f2bf(v.w);
        ((ushort4*)Xb)[i] = o;
    } else if (i < NXU + NW1) {
        const int idx4 = (i - NXU) * 4;
        const int row = idx4 >> 10, col = idx4 & 1023;
        float4 v;
        if      (row < 1024) v = *(const float4*)(Wq + (size_t)row*HID + col);
        else if (row < 2048) v = *(const float4*)(Wk + (size_t)(row-1024)*HID + col);
        else if (row < 3072) v = *(const float4*)(Wv + (size_t)(row-2048)*HID + col);
        else if (row < 3088) v = *(const float4*)(Wf + (size_t)(row-3072)*HID + col);
        else                 v = make_float4(0.f,0.f,0.f,0.f);
        ushort4 o; o.x=f2bf(v.x); o.y=f2bf(v.y); o.z=f2bf(v.z); o.w=f2bf(v.w);
        *(ushort4*)(Wstk + idx4) = o;
    } else if (i < NXU + NW1 + NW2) {
        const int idx4 = (i - NXU - NW1) * 4;
        float4 v = *(const float4*)(Wo + idx4);
        ushort4 o; o.x=f2bf(v.x); o.y=f2bf(v.y); o.z=f2bf(v.z); o.w=f2bf(v.w);
        *(ushort4*)(Wob + idx4) = o;
    } else if (i < NTOT) {
        const int idx4 = (i - NXU - NW1 - NW2) * 4;
        #pragma unroll
        for (int t = 0; t < 4; ++t) {
            const int c = idx4 + t;
            float v;
            if      (c < 1024) v = bq[c];
            else if (c < 2048) v = bk[c-1024];
            else if (c < 3072) v = bv[c-2048];
            else if (c < 3088) v = bf[c-3072];
            else               v = 0.f;
            bstk[c] = v;
        }
    }
}

// ---------------------------------------------------------------------------
// Fused QKV+F GEMM (16x16x32 MFMA) — round-0/3/6 verified structure.
// Grid: x = ROW panel (64), y = COL panel (25).
// ---------------------------------------------------------------------------
__global__ __launch_bounds__(256) void qkvf_gemm(
    const ushort_t* __restrict__ X, const ushort_t* __restrict__ W,
    const float* __restrict__ bias,
    ushort_t* __restrict__ Q, ushort_t* __restrict__ Kr,
    ushort_t* __restrict__ V,
    float* __restrict__ f_out, float* __restrict__ logf_out)
{
    __shared__ ushort_t As[128 * 32];
    __shared__ ushort_t Bs[128 * 32];

    const int tid  = threadIdx.x;
    const int wave = tid >> 6, lane = tid & 63;
    const int waveM = wave >> 1, waveN = wave & 1;
    const int rowBase = blockIdx.x * 128;
    const int colBase = blockIdx.y * 128;
    const int K = HID;

    f32x4 acc[4][4];
    #pragma unroll
    for (int i = 0; i < 4; ++i)
        #pragma unroll
        for (int j = 0; j < 4; ++j)
            acc[i][j] = (f32x4){0.f, 0.f, 0.f, 0.f};

    const int srow = lane >> 2;
    const int scol = (lane & 3) * 8;

    const ushort_t* gA0 = X + (size_t)(rowBase + wave*16 + srow) * K + scol;
    const ushort_t* gB0 = W + (size_t)(colBase + wave*16 + srow) * K + scol;
    ushort_t* lA = As + (wave*16)*32;
    ushort_t* lB = Bs + (wave*16)*32;

    const int fr = lane & 15;
    const int fk = (lane >> 4) * 8;

    for (int k0 = 0; k0 < K; k0 += 32) {
        GLL16(gA0 + k0,                lA);
        GLL16(gA0 + (size_t)64*K + k0, lA + 64*32);
        GLL16(gB0 + k0,                lB);
        GLL16(gB0 + (size_t)64*K + k0, lB + 64*32);

        __syncthreads();

        bf16x8 a[4], b[4];
        #pragma unroll
        for (int i = 0; i < 4; ++i)
            a[i] = *(const bf16x8*)(As + (waveM*64 + i*16 + fr)*32 + fk);
        #pragma unroll
        for (int j = 0; j < 4; ++j)
            b[j] = *(const bf16x8*)(Bs + (waveN*64 + j*16 + fr)*32 + fk);

        #pragma unroll
        for (int i = 0; i < 4; ++i)
            #pragma unroll
            for (int j = 0; j < 4; ++j)
                acc[i][j] = __builtin_amdgcn_mfma_f32_16x16x32_bf16(
                    a[i], b[j], acc[i][j], 0, 0, 0);

        __syncthreads();
    }

    const int er = (lane >> 4) * 4;
    const int ec = lane & 15;
    #pragma unroll
    for (int i = 0; i < 4; ++i) {
        #pragma unroll
        for (int j = 0; j < 4; ++j) {
            const int r0 = rowBase + waveM*64 + i*16 + er;
            const int c0 = colBase + waveN*64 + j*16;        // lane-uniform
            if (c0 >= 3088) continue;
            const int c  = c0 + ec;
            const float bv = bias[c];
            #pragma unroll
            for (int k = 0; k < 4; ++k) {
                float v = acc[i][j][k] + bv;
                const int r = r0 + k;
                if (c0 < 1024) {
                    v = (v > 0.f) ? (v + 1.f) : __expf(v);
                    Q[(size_t)r * HID + c] = f2bf(v);
                } else if (c0 < 2048) {
                    v = (v > 0.f) ? (v + 1.f) : __expf(v);
                    Kr[(size_t)r * HID + (c - 1024)] = f2bf(v);
                } else if (c0 < 3072) {
                    V[(size_t)r * HID + (c - 2048)] = f2bf(v);
                } else {
                    const int n = c - 3072;
                    const float fv = 1.f / (1.f + __expf(-v));
                    f_out[(size_t)r * HEADS + n]    = fv;
                    logf_out[(size_t)r * HEADS + n] = -__logf(1.f + __expf(-v));
                }
            }
        }
    }
}

// ---------------------------------------------------------------------------
// Output GEMM: out = AO @ Wo^T + bo (fp32) — round-0/3/6 structure.
// Zero-fill of slot 1 via hipMemsetAsync in launcher.
// ---------------------------------------------------------------------------
__global__ __launch_bounds__(256) void gemm_out(
    const ushort_t* __restrict__ X, const ushort_t* __restrict__ W,
    const float* __restrict__ bias, float* __restrict__ Y)
{
    __shared__ ushort_t As[128 * 32];
    __shared__ ushort_t Bs[128 * 32];

    const int tid  = threadIdx.x;
    const int wave = tid >> 6, lane = tid & 63;
    const int waveM = wave >> 1, waveN = wave & 1;
    const int rowBase = blockIdx.x * 128;
    const int colBase = blockIdx.y * 128;
    const int K = HID, N = HID;

    f32x4 acc[4][4];
    #pragma unroll
    for (int i = 0; i < 4; ++i)
        #pragma unroll
        for (int j = 0; j < 4; ++j)
            acc[i][j] = (f32x4){0.f, 0.f, 0.f, 0.f};

    const int srow = lane >> 2;
    const int scol = (lane & 3) * 8;

    const ushort_t* gA0 = X + (size_t)(rowBase + wave*16 + srow) * K + scol;
    const ushort_t* gB0 = W + (size_t)(colBase + wave*16 + srow) * K + scol;
    ushort_t* lA = As + (wave*16)*32;
    ushort_t* lB = Bs + (wave*16)*32;

    const int fr = lane & 15;
    const int fk = (lane >> 4) * 8;

    for (int k0 = 0; k0 < K; k0 += 32) {
        GLL16(gA0 + k0,                lA);
        GLL16(gA0 + (size_t)64*K + k0, lA + 64*32);
        GLL16(gB0 + k0,                lB);
        GLL16(gB0 + (size_t)64*K + k0, lB + 64*32);

        __syncthreads();

        bf16x8 a[4], b[4];
        #pragma unroll
        for (int i = 0; i < 4; ++i)
            a[i] = *(const bf16x8*)(As + (waveM*64 + i*16 + fr)*32 + fk);
        #pragma unroll
        for (int j = 0; j < 4; ++j)
            b[j] = *(const bf16x8*)(Bs + (waveN*64 + j*16 + fr)*32 + fk);

        #pragma unroll
        for (int i = 0; i < 4; ++i)
            #pragma unroll
            for (int j = 0; j < 4; ++j)
                acc[i][j] = __builtin_amdgcn_mfma_f32_16x16x32_bf16(
                    a[i], b[j], acc[i][j], 0, 0, 0);

        __syncthreads();
    }

    const int er = (lane >> 4) * 4;
    const int ec = lane & 15;
    #pragma unroll
    for (int i = 0; i < 4; ++i) {
        #pragma unroll
        for (int j = 0; j < 4; ++j) {
            const int r0 = rowBase + waveM*64 + i*16 + er;
            const int c  = colBase + waveN*64 + j*16 + ec;
            const float bv = bias[c];
            #pragma unroll
            for (int k = 0; k < 4; ++k) {
                const size_t off = (size_t)(r0 + k) * N + c;
                Y[off] = acc[i][j][k] + bv;
            }
        }
    }
}

// ---------------------------------------------------------------------------
// Pass 1 (MFMA): ScT[e][d] = sum_j v[j][e]*(exd_j k[j][d]); z[d] likewise.
// Transposed LDS tiles use JSW write/read swizzle.
// ---------------------------------------------------------------------------
__global__ __launch_bounds__(256) void pass1_kernel(
    const ushort_t* __restrict__ Kp, const ushort_t* __restrict__ Vp,
    const float* __restrict__ logf,
    ushort_t* __restrict__ Schunk, float* __restrict__ zchunk,
    float* __restrict__ Dchunk)
{
    __shared__ __align__(16) char smem[18688];
    ushort_t* vsT = (ushort_t*)smem;            // [64][72]: row e, col j (JSW)
    ushort_t* kTd = (ushort_t*)(smem + 9216);   // [64][72]: row d, col j (JSW)
    float*    exd = (float*)(smem + 18432);     // [64]

    const int chunk = blockIdx.x;
    const int bh = blockIdx.y;
    const int b = bh >> 4, h = bh & 15;
    const int tid = threadIdx.x;
    const int wv = tid >> 6, ln = tid & 63;
    const int fr = ln & 15, q4 = ln >> 4;
    const size_t slot = (size_t)bh * NCHUNK + chunk;

    u16x8 vreg[2], kreg[2];
    #pragma unroll
    for (int it = 0; it < 2; ++it) {
        const int u = it*256 + tid;
        const int j = u >> 3, d8 = (u & 7) * 8;
        const size_t base = (size_t)((chunk*64 + j)*BATCH + b)*HID + h*HD + d8;
        vreg[it] = *(const u16x8*)(Vp + base);
        kreg[it] = *(const u16x8*)(Kp + base);
    }
    if (tid < 64) {
        float v = logf[(size_t)((chunk*64 + tid)*BATCH + b) * HEADS + h];
        #pragma unroll
        for (int off = 1; off < 64; off <<= 1) {
            float n = __shfl_up(v, off);
            if (tid >= off) v += n;
        }
        const float tot = __shfl(v, 63);
        exd[tid] = __expf(tot - v);
        if (tid == 63) Dchunk[slot] = __expf(tot);
    }
    __syncthreads();

    #pragma unroll
    for (int it = 0; it < 2; ++it) {
        const int u = it*256 + tid;
        const int j = u >> 3, d8 = (u & 7) * 8;
        const int js = j ^ ((u & 7) << 3);       // JSW(d8+i, j), (d8+i)>>3 == u&7
        const float ex = exd[j];
        #pragma unroll
        for (int i = 0; i < 8; ++i) {
            vsT[(d8+i)*72 + js] = vreg[it][i];
            kTd[(d8+i)*72 + js] = f2bf(bf2f(kreg[it][i]) * ex);
        }
    }
    __syncthreads();

    f32x4 acc[4];
    #pragma unroll
    for (int nt = 0; nt < 4; ++nt) acc[nt] = (f32x4){0.f,0.f,0.f,0.f};
    #pragma unroll
    for (int k0 = 0; k0 < 64; k0 += 32) {
        const int rA = wv*16 + fr;
        bf16x8 av = *(const bf16x8*)(vsT + rA*72 + JSW(rA, k0 + q4*8));
        #pragma unroll
        for (int nt = 0; nt < 4; ++nt) {
            const int rB = nt*16 + fr;
            bf16x8 bk = *(const bf16x8*)(kTd + rB*72 + JSW(rB, k0 + q4*8));
            acc[nt] = __builtin_amdgcn_mfma_f32_16x16x32_bf16(av, bk, acc[nt], 0, 0, 0);
        }
    }

    if (wv == 0) {
        u16x8 onesu;
        #pragma unroll
        for (int i = 0; i < 8; ++i) onesu[i] = 0x3F80;   // bf16 1.0
        const bf16x8 ones = *(const bf16x8*)&onesu;
        f32x4 zacc[4];
        #pragma unroll
        for (int nt = 0; nt < 4; ++nt) zacc[nt] = (f32x4){0.f,0.f,0.f,0.f};
        #pragma unroll
        for (int k0 = 0; k0 < 64; k0 += 32) {
            #pragma unroll
            for (int nt = 0; nt < 4; ++nt) {
                const int rB = nt*16 + fr;
                bf16x8 bk = *(const bf16x8*)(kTd + rB*72 + JSW(rB, k0 + q4*8));
                zacc[nt] = __builtin_amdgcn_mfma_f32_16x16x32_bf16(ones, bk, zacc[nt], 0, 0, 0);
            }
        }
        if (q4 == 0) {
            #pragma unroll
            for (int nt = 0; nt < 4; ++nt)
                zchunk[slot*64 + nt*16 + fr] = zacc[nt][0];
        }
    }

    ushort_t* sp = Schunk + slot * 4096;
    #pragma unroll
    for (int nt = 0; nt < 4; ++nt) {
        #pragma unroll
        for (int r = 0; r < 4; ++r) {
            const int e = wv*16 + q4*4 + r;
            sp[e*64 + nt*16 + fr] = f2bf(acc[nt][r]);
        }
    }
}

// ---------------------------------------------------------------------------
// Pass 2: sequential over 32 chunks; 512 blocks (8 slices per bh), 128 thr,
// 4 bf16/thread via u16x4 (8B/lane), depth-2 prefetch.
// ---------------------------------------------------------------------------
__global__ __launch_bounds__(128) void pass2_kernel(
    ushort_t* __restrict__ Schunk, float* __restrict__ zchunk,
    const float* __restrict__ Dchunk)
{
    __shared__ float Ds[NCHUNK];
    const int bh  = blockIdx.x >> 3;
    const int sl  = blockIdx.x & 7;
    const int tid = threadIdx.x;

    if (tid < NCHUNK) Ds[tid] = Dchunk[bh * NCHUNK + tid];

    float Sprev[4] = {0.f, 0.f, 0.f, 0.f};
    float zprev = 0.f;

    const size_t base  = (size_t)bh * NCHUNK * 4096 + sl * 512 + tid * 4;
    const size_t zbase = (size_t)bh * NCHUNK * 64;
    const bool doZ = (sl == 0) && (tid < 64);

    u16x4 b0 = *(const u16x4*)(Schunk + base);
    u16x4 b1 = *(const u16x4*)(Schunk + base + 4096);
    float z0v = 0.f, z1v = 0.f;
    if (doZ) {
        z0v = zchunk[zbase + tid];
        z1v = zchunk[zbase + 64 + tid];
    }
    __syncthreads();

    for (int c = 0; c < NCHUNK; ++c) {
        const float D = Ds[c];
        ushort_t* sp = Schunk + base + (size_t)c * 4096;
        u16x4 wout;
        #pragma unroll
        for (int i = 0; i < 4; ++i) {
            wout[i] = f2bf(Sprev[i]);
            Sprev[i] = D * Sprev[i] + bf2f(b0[i]);
        }
        *(u16x4*)sp = wout;
        b0 = b1;
        if (doZ) {
            zchunk[zbase + (size_t)c * 64 + tid] = zprev;
            zprev = D * zprev + z0v;
            z0v = z1v;
        }
        if (c + 2 < NCHUNK) {
            b1 = *(const u16x4*)(Schunk + base + (size_t)(c+2)*4096);
            if (doZ) z1v = zchunk[zbase + (size_t)(c+2)*64 + tid];
        }
    }
}

// ---------------------------------------------------------------------------
// Pass 3 (full-MFMA): per (bh, chunk) attention outputs -> bf16 AO.
// vsT transpose scatter uses JSW. S0 B-fragments are PREFETCHED into
// registers at kernel entry (round-8 win: they overlap QK^T + softmax +
// two barriers instead of sitting exposed on the final-loop critical path).
// ---------------------------------------------------------------------------
__global__ __launch_bounds__(256) void pass3_kernel(
    const ushort_t* __restrict__ Qp, const ushort_t* __restrict__ Kp,
    const ushort_t* __restrict__ Vp, const float* __restrict__ logf,
    const ushort_t* __restrict__ S0, const float* __restrict__ z0,
    ushort_t* __restrict__ AO)
{
    __shared__ __align__(16) char smem[28928];
    ushort_t* qs  = (ushort_t*)smem;               // [64][72] (t rows)
    ushort_t* ks  = (ushort_t*)(smem + 9216);      // [64][72] (j rows) phase A
    ushort_t* vsT = (ushort_t*)(smem + 9216);      // [64][72] (e rows, JSW) phase B
    ushort_t* psA = (ushort_t*)(smem + 18432);     // [64][72] P
    float* cc  = (float*)(smem + 27648);
    float* exT = (float*)(smem + 27904);
    float* qz  = (float*)(smem + 28160);
    float* den = (float*)(smem + 28416);
    float* zz  = (float*)(smem + 28672);

    const int chunk = blockIdx.x;
    const int bh = blockIdx.y;
    const int b = bh >> 4, h = bh & 15;
    const int tid = threadIdx.x;
    const int wv = tid >> 6, ln = tid & 63;
    const int fr = ln & 15, q4 = ln >> 4;
    const size_t slot = (size_t)bh * NCHUNK + chunk;

    // prefetch V rows into registers (scattered to LDS after B2)
    u16x8 vreg[2];
    #pragma unroll
    for (int it = 0; it < 2; ++it) {
        const int u = it*256 + tid;
        const int j = u >> 3, d8 = (u & 7) * 8;
        vreg[it] = *(const u16x8*)(Vp + (size_t)((chunk*64 + j)*BATCH + b)*HID + h*HD + d8);
    }
    // prefetch S0 B-fragments into registers (consumed after B3)
    bf16x8 s0r[4][2];
    {
        const ushort_t* S0p = S0 + slot * 4096;
        #pragma unroll
        for (int nt = 0; nt < 4; ++nt)
            #pragma unroll
            for (int kk = 0; kk < 2; ++kk)
                s0r[nt][kk] = *(const bf16x8*)(S0p + (nt*16 + fr)*64 + kk*32 + q4*8);
    }

    if (tid < 64) {
        zz[tid] = z0[slot * 64 + tid];
        float v = logf[(size_t)((chunk*64 + tid)*BATCH + b) * HEADS + h];
        #pragma unroll
        for (int off = 1; off < 64; off <<= 1) {
            float n = __shfl_up(v, off);
            if (tid >= off) v += n;
        }
        cc[tid]  = v;
        exT[tid] = __expf(v);
    }
    #pragma unroll
    for (int it = 0; it < 2; ++it) {
        const int u = it*256 + tid;
        const int r = u >> 3, c8 = (u & 7) * 8;
        const size_t goff = (size_t)((chunk*64 + r)*BATCH + b) * HID + h*HD + c8;
        *(u16x8*)(qs + r*72 + c8) = *(const u16x8*)(Qp + goff);
        *(u16x8*)(ks + r*72 + c8) = *(const u16x8*)(Kp + goff);
    }
    __syncthreads();   // B1

    f32x4 pacc[4];
    #pragma unroll
    for (int nt = 0; nt < 4; ++nt) pacc[nt] = (f32x4){0.f,0.f,0.f,0.f};
    #pragma unroll
    for (int k0 = 0; k0 < 64; k0 += 32) {
        bf16x8 af = *(const bf16x8*)(qs + (wv*16 + fr)*72 + k0 + q4*8);
        #pragma unroll
        for (int nt = 0; nt < 4; ++nt) {
            bf16x8 bfr = *(const bf16x8*)(ks + (nt*16 + fr)*72 + k0 + q4*8);
            pacc[nt] = __builtin_amdgcn_mfma_f32_16x16x32_bf16(af, bfr, pacc[nt], 0, 0, 0);
        }
    }
    // qz[t], t = wv*16+fr, all waves: 16-elem partials over d + xor-reduce
    {
        const int t = wv*16 + fr;
        const int d0 = q4 * 16;
        float s = 0.f;
        #pragma unroll
        for (int i = 0; i < 16; ++i)
            s += bf2f(qs[t*72 + d0 + i]) * zz[d0 + i];
        s += __shfl_xor(s, 16);
        s += __shfl_xor(s, 32);
        if (q4 == 0) qz[t] = s;
    }
    __syncthreads();   // B2 — ks reads done; vsT may overwrite

    #pragma unroll
    for (int it = 0; it < 2; ++it) {
        const int u = it*256 + tid;
        const int j = u >> 3, d8 = (u & 7) * 8;
        const int js = j ^ ((u & 7) << 3);       // JSW(d8+i, j)
        #pragma unroll
        for (int i = 0; i < 8; ++i)
            vsT[(d8+i)*72 + js] = vreg[it][i];
    }
    {
        float rs[4] = {0.f, 0.f, 0.f, 0.f};
        float cct[4];
        #pragma unroll
        for (int r = 0; r < 4; ++r) cct[r] = cc[wv*16 + q4*4 + r];
        #pragma unroll
        for (int nt = 0; nt < 4; ++nt) {
            const int j = nt*16 + fr;
            const float ccj = cc[j];
            #pragma unroll
            for (int r = 0; r < 4; ++r) {
                const int t = wv*16 + q4*4 + r;
                float p = (j <= t) ? pacc[nt][r] * __expf(cct[r] - ccj) : 0.f;
                rs[r] += p;
                psA[t*72 + j] = f2bf(p);
            }
        }
        #pragma unroll
        for (int m = 1; m < 16; m <<= 1) {
            #pragma unroll
            for (int r = 0; r < 4; ++r) rs[r] += __shfl_xor(rs[r], m);
        }
        if (fr == 0) {
            #pragma unroll
            for (int r = 0; r < 4; ++r) {
                const int t = wv*16 + q4*4 + r;
                den[t] = rs[r] + exT[t] * qz[t] + 1e-6f;
            }
        }
    }
    __syncthreads();   // B3

    f32x4 oacc[4], oacc2[4];
    #pragma unroll
    for (int nt = 0; nt < 4; ++nt) {
        oacc[nt]  = (f32x4){0.f,0.f,0.f,0.f};
        oacc2[nt] = (f32x4){0.f,0.f,0.f,0.f};
    }
    #pragma unroll
    for (int kk = 0; kk < 2; ++kk) {
        const int k8 = kk*32 + q4*8;
        bf16x8 ap = *(const bf16x8*)(psA + (wv*16 + fr)*72 + k8);
        bf16x8 aq = *(const bf16x8*)(qs  + (wv*16 + fr)*72 + k8);
        #pragma unroll
        for (int nt = 0; nt < 4; ++nt) {
            const int rV = nt*16 + fr;
            bf16x8 bv = *(const bf16x8*)(vsT + rV*72 + JSW(rV, k8));
            oacc[nt] = __builtin_amdgcn_mfma_f32_16x16x32_bf16(ap, bv, oacc[nt], 0, 0, 0);
            oacc2[nt] = __builtin_amdgcn_mfma_f32_16x16x32_bf16(aq, s0r[nt][kk], oacc2[nt], 0, 0, 0);
        }
    }
    #pragma unroll
    for (int nt = 0; nt < 4; ++nt) {
        const int e = nt*16 + fr;
        #pragma unroll
        for (int r = 0; r < 4; ++r) {
            const int t = wv*16 + q4*4 + r;
            const float v = (oacc[nt][r] + exT[t] * oacc2[nt][r]) / den[t];
            AO[(size_t)((chunk*64 + t)*BATCH + b) * HID + h*HD + e] = f2bf(v);
        }
    }
}

// ---------------------------------------------------------------------------
extern "C" void kernel_launch(void* const* d_in, const int* in_sizes, int n_in,
                              void* d_out, int out_size, void* d_ws, size_t ws_size,
                              hipStream_t stream) {
    const float* X  = (const float*)d_in[0];
    const float* Wq = (const float*)d_in[1];
    const float* bq = (const float*)d_in[2];
    const float* Wk = (const float*)d_in[3];
    const float* bk = (const float*)d_in[4];
    const float* Wv = (const float*)d_in[5];
    const float* bv = (const float*)d_in[6];
    const float* Wf = (const float*)d_in[7];
    const float* bf = (const float*)d_in[8];
    const float* Wo = (const float*)d_in[9];
    const float* bo = (const float*)d_in[10];

    float* out = (float*)d_out;
    const size_t OUT_SLOT = (size_t)SB * HID;

    char* ws = (char*)d_ws;
    ushort_t* wsXb   = (ushort_t*)ws;                       // SB*HID bf16 (X, later AO)
    ushort_t* wsWstk = wsXb + (size_t)SB * HID;             // NSTK*HID bf16
    ushort_t* wsWob  = wsWstk + (size_t)NSTK * HID;         // HID*HID bf16
    ushort_t* wsQ    = wsWob + (size_t)HID * HID;           // [row][col]
    ushort_t* wsK    = wsQ + (size_t)SB * HID;              // [row][col]
    ushort_t* wsV    = wsK + (size_t)SB * HID;              // [row][col]
    float* wsBstk = (float*)(wsV + (size_t)SB * HID);       // NSTK fp32
    float* wsLogf = wsBstk + NSTK;                          // SB*HEADS fp32
    ushort_t* wsS  = (ushort_t*)(wsLogf + (size_t)SB * HEADS); // bf16 S^T chunks -> S0^T
    float* wsZ    = (float*)(wsS + (size_t)BH * NCHUNK * HD * HD);
    float* wsD    = wsZ + (size_t)BH * NCHUNK * HD;

    // zero slot 1 (second output) via memset node
    hipMemsetAsync(out + OUT_SLOT, 0, OUT_SLOT * sizeof(float), stream);

    prep_kernel<<<(NTOT + 255)/256, 256, 0, stream>>>(
        X, Wq, Wk, Wv, Wf, Wo, bq, bk, bv, bf,
        wsXb, wsWstk, wsWob, wsBstk);

    dim3 qgrid(SB/128, NSTK/128);   // x = row (64), y = col (25)
    qkvf_gemm<<<qgrid, 256, 0, stream>>>(
        wsXb, wsWstk, wsBstk, wsQ, wsK, wsV,
        out + 2*OUT_SLOT, wsLogf);

    dim3 sgrid(NCHUNK, BH);
    pass1_kernel<<<sgrid, 256, 0, stream>>>(wsK, wsV, wsLogf, wsS, wsZ, wsD);
    pass2_kernel<<<BH*8, 128, 0, stream>>>(wsS, wsZ, wsD);
    pass3_kernel<<<sgrid, 256, 0, stream>>>(wsQ, wsK, wsV, wsLogf, wsS, wsZ, wsXb);

    dim3 ogrid(SB/128, HID/128);    // x = row (64), y = col (8)
    gemm_out<<<ogrid, 256, 0, stream>>>(wsXb, wsWob, bo, out);
}

// Round 11
// 275.883 us; speedup vs baseline: 1.0292x; 1.0156x over previous
//
#include <hip/hip_runtime.h>
#include <hip/hip_bf16.h>
#include <math.h>

// Problem constants
#define S_LEN 2048
#define BATCH 4
#define HID   1024
#define HEADS 16
#define HD    64
#define SB    (S_LEN*BATCH)       // 8192 rows
#define CHUNK 64
#define NCHUNK (S_LEN/CHUNK)      // 32
#define BH    (BATCH*HEADS)       // 64
#define NSTK  3200                // 1024*3 (QKV) + 16 (F) padded to 25*128

typedef __bf16 bf16x8 __attribute__((ext_vector_type(8)));
typedef float  f32x4  __attribute__((ext_vector_type(4)));
typedef unsigned short ushort_t;
typedef unsigned short u16x8 __attribute__((ext_vector_type(8)));
typedef unsigned short u16x4 __attribute__((ext_vector_type(4)));

__device__ __forceinline__ unsigned short f2bf(float x) {
    union { float f; unsigned int u; } un; un.f = x;
    unsigned int u = un.u;
    unsigned int r = (u + 0x7FFFu + ((u >> 16) & 1u)) >> 16;  // RNE
    return (unsigned short)r;
}
__device__ __forceinline__ float bf2f(unsigned short s) {
    union { unsigned int u; float f; } un; un.u = ((unsigned int)s) << 16;
    return un.f;
}

// XOR j-block swizzle for [64][72] transposed LDS tiles: spreads the
// 8-row-stride scatter writes across all banks; reads stay 16B-contiguous.
#define JSW(row, j) ((j) ^ ((((row) >> 3) & 7) << 3))

#define GLL16(src, dst) __builtin_amdgcn_global_load_lds( \
    (const __attribute__((address_space(1))) void*)(src), \
    (__attribute__((address_space(3))) void*)(dst), 16, 0, 0)

// ---------------------------------------------------------------------------
// Prep kernel (one dispatch): X->bf16; Wstk build; Wo->bf16; bstk build.
// ---------------------------------------------------------------------------
#define NXU (SB*HID/4)          // 2097152
#define NW1 (NSTK*HID/4)        // 819200
#define NW2 (HID*HID/4)         // 262144
#define NBU (NSTK/4)            // 800
#define NTOT (NXU+NW1+NW2+NBU)

__global__ __launch_bounds__(256) void prep_kernel(
    const float* __restrict__ X,  const float* __restrict__ Wq,
    const float* __restrict__ Wk, const float* __restrict__ Wv,
    const float* __restrict__ Wf, const float* __restrict__ Wo,
    const float* __restrict__ bq, const float* __restrict__ bk,
    const float* __restrict__ bv, const float* __restrict__ bf,
    ushort_t* __restrict__ Xb, ushort_t* __restrict__ Wstk,
    ushort_t* __restrict__ Wob, float* __restrict__ bstk)
{
    const int i = blockIdx.x * 256 + threadIdx.x;
    if (i < NXU) {
        float4 v = ((const float4*)X)[i];
        ushort4 o; o.x=f2bf(v.x); o.y=f2bf(v.y); o.z=f2bf(v.z); o.w=f2bf(v.w);
        ((ushort4*)Xb)[i] = o;
    } else if (i < NXU + NW1) {
        const int idx4 = (i - NXU) * 4;
        const int row = idx4 >> 10, col = idx4 & 1023;
        float4 v;
        if      (row < 1024) v = *(const float4*)(Wq + (size_t)row*HID + col);
        else if (row < 2048) v = *(const float4*)(Wk + (size_t)(row-1024)*HID + col);
        else if (row < 3072) v = *(const float4*)(Wv + (size_t)(row-2048)*HID + col);
        else if (row < 3088) v = *(const float4*)(Wf + (size_t)(row-3072)*HID + col);
        else                 v = make_float4(0.f,0.f,0.f,0.f);
        ushort4 o; o.x=f2bf(v.x); o.y=f2bf(v.y); o.z=f2bf(v.z); o.w=f2bf(v.w);
        *(ushort4*)(Wstk + idx4) = o;
    } else if (i < NXU + NW1 + NW2) {
        const int idx4 = (i - NXU - NW1) * 4;
        float4 v = *(const float4*)(Wo + idx4);
        ushort4 o; o.x=f2bf(v.x); o.y=f2bf(v.y); o.z=f2bf(v.z); o.w=f2bf(v.w);
        *(ushort4*)(Wob + idx4) = o;
    } else if (i < NTOT) {
        const int idx4 = (i - NXU - NW1 - NW2) * 4;
        #pragma unroll
        for (int t = 0; t < 4; ++t) {
            const int c = idx4 + t;
            float v;
            if      (c < 1024) v = bq[c];
            else if (c < 2048) v = bk[c-1024];
            else if (c < 3072) v = bv[c-2048];
            else if (c < 3088) v = bf[c-3072];
            else               v = 0.f;
            bstk[c] = v;
        }
    }
}

// ---------------------------------------------------------------------------
// Fused QKV+F GEMM (16x16x32 MFMA) — verified 2-barrier loop, now 8 waves
// per 128x128 tile (wave grid 2M x 4N, acc[4][2], ~100 VGPR) so TWO blocks
// co-reside per CU (16 waves/CU vs 8) to hide the per-iteration drain.
// Grid: x = ROW panel (64), y = COL panel (25). Block = 512 threads.
// ---------------------------------------------------------------------------
__global__ __launch_bounds__(512, 4) void qkvf_gemm(
    const ushort_t* __restrict__ X, const ushort_t* __restrict__ W,
    const float* __restrict__ bias,
    ushort_t* __restrict__ Q, ushort_t* __restrict__ Kr,
    ushort_t* __restrict__ V,
    float* __restrict__ f_out, float* __restrict__ logf_out)
{
    __shared__ ushort_t As[128 * 32];
    __shared__ ushort_t Bs[128 * 32];

    const int tid  = threadIdx.x;
    const int wave = tid >> 6, lane = tid & 63;   // wave 0..7
    const int waveM = wave >> 2, waveN = wave & 3;
    const int rowBase = blockIdx.x * 128;
    const int colBase = blockIdx.y * 128;
    const int K = HID;

    f32x4 acc[4][2];
    #pragma unroll
    for (int i = 0; i < 4; ++i)
        #pragma unroll
        for (int j = 0; j < 2; ++j)
            acc[i][j] = (f32x4){0.f, 0.f, 0.f, 0.f};

    const int srow = lane >> 2;
    const int scol = (lane & 3) * 8;

    // each of 8 waves stages one 16-row chunk of A and of B per K-step
    const ushort_t* gA0 = X + (size_t)(rowBase + wave*16 + srow) * K + scol;
    const ushort_t* gB0 = W + (size_t)(colBase + wave*16 + srow) * K + scol;
    ushort_t* lA = As + (wave*16)*32;
    ushort_t* lB = Bs + (wave*16)*32;

    const int fr = lane & 15;
    const int fk = (lane >> 4) * 8;

    for (int k0 = 0; k0 < K; k0 += 32) {
        GLL16(gA0 + k0, lA);
        GLL16(gB0 + k0, lB);

        __syncthreads();

        bf16x8 a[4], b[2];
        #pragma unroll
        for (int i = 0; i < 4; ++i)
            a[i] = *(const bf16x8*)(As + (waveM*64 + i*16 + fr)*32 + fk);
        #pragma unroll
        for (int j = 0; j < 2; ++j)
            b[j] = *(const bf16x8*)(Bs + (waveN*32 + j*16 + fr)*32 + fk);

        #pragma unroll
        for (int i = 0; i < 4; ++i)
            #pragma unroll
            for (int j = 0; j < 2; ++j)
                acc[i][j] = __builtin_amdgcn_mfma_f32_16x16x32_bf16(
                    a[i], b[j], acc[i][j], 0, 0, 0);

        __syncthreads();
    }

    const int er = (lane >> 4) * 4;
    const int ec = lane & 15;
    #pragma unroll
    for (int i = 0; i < 4; ++i) {
        #pragma unroll
        for (int j = 0; j < 2; ++j) {
            const int r0 = rowBase + waveM*64 + i*16 + er;
            const int c0 = colBase + waveN*32 + j*16;        // lane-uniform
            if (c0 >= 3088) continue;
            const int c  = c0 + ec;
            const float bv = bias[c];
            #pragma unroll
            for (int k = 0; k < 4; ++k) {
                float v = acc[i][j][k] + bv;
                const int r = r0 + k;
                if (c0 < 1024) {
                    v = (v > 0.f) ? (v + 1.f) : __expf(v);
                    Q[(size_t)r * HID + c] = f2bf(v);
                } else if (c0 < 2048) {
                    v = (v > 0.f) ? (v + 1.f) : __expf(v);
                    Kr[(size_t)r * HID + (c - 1024)] = f2bf(v);
                } else if (c0 < 3072) {
                    V[(size_t)r * HID + (c - 2048)] = f2bf(v);
                } else {
                    const int n = c - 3072;
                    const float fv = 1.f / (1.f + __expf(-v));
                    f_out[(size_t)r * HEADS + n]    = fv;
                    logf_out[(size_t)r * HEADS + n] = -__logf(1.f + __expf(-v));
                }
            }
        }
    }
}

// ---------------------------------------------------------------------------
// Output GEMM: out = AO @ Wo^T + bo (fp32) — same 8-wave occupancy variant.
// Zero-fill of slot 1 via hipMemsetAsync in launcher.
// ---------------------------------------------------------------------------
__global__ __launch_bounds__(512, 4) void gemm_out(
    const ushort_t* __restrict__ X, const ushort_t* __restrict__ W,
    const float* __restrict__ bias, float* __restrict__ Y)
{
    __shared__ ushort_t As[128 * 32];
    __shared__ ushort_t Bs[128 * 32];

    const int tid  = threadIdx.x;
    const int wave = tid >> 6, lane = tid & 63;   // wave 0..7
    const int waveM = wave >> 2, waveN = wave & 3;
    const int rowBase = blockIdx.x * 128;
    const int colBase = blockIdx.y * 128;
    const int K = HID, N = HID;

    f32x4 acc[4][2];
    #pragma unroll
    for (int i = 0; i < 4; ++i)
        #pragma unroll
        for (int j = 0; j < 2; ++j)
            acc[i][j] = (f32x4){0.f, 0.f, 0.f, 0.f};

    const int srow = lane >> 2;
    const int scol = (lane & 3) * 8;

    const ushort_t* gA0 = X + (size_t)(rowBase + wave*16 + srow) * K + scol;
    const ushort_t* gB0 = W + (size_t)(colBase + wave*16 + srow) * K + scol;
    ushort_t* lA = As + (wave*16)*32;
    ushort_t* lB = Bs + (wave*16)*32;

    const int fr = lane & 15;
    const int fk = (lane >> 4) * 8;

    for (int k0 = 0; k0 < K; k0 += 32) {
        GLL16(gA0 + k0, lA);
        GLL16(gB0 + k0, lB);

        __syncthreads();

        bf16x8 a[4], b[2];
        #pragma unroll
        for (int i = 0; i < 4; ++i)
            a[i] = *(const bf16x8*)(As + (waveM*64 + i*16 + fr)*32 + fk);
        #pragma unroll
        for (int j = 0; j < 2; ++j)
            b[j] = *(const bf16x8*)(Bs + (waveN*32 + j*16 + fr)*32 + fk);

        #pragma unroll
        for (int i = 0; i < 4; ++i)
            #pragma unroll
            for (int j = 0; j < 2; ++j)
                acc[i][j] = __builtin_amdgcn_mfma_f32_16x16x32_bf16(
                    a[i], b[j], acc[i][j], 0, 0, 0);

        __syncthreads();
    }

    const int er = (lane >> 4) * 4;
    const int ec = lane & 15;
    #pragma unroll
    for (int i = 0; i < 4; ++i) {
        #pragma unroll
        for (int j = 0; j < 2; ++j) {
            const int r0 = rowBase + waveM*64 + i*16 + er;
            const int c  = colBase + waveN*32 + j*16 + ec;
            const float bv = bias[c];
            #pragma unroll
            for (int k = 0; k < 4; ++k) {
                const size_t off = (size_t)(r0 + k) * N + c;
                Y[off] = acc[i][j][k] + bv;
            }
        }
    }
}

// ---------------------------------------------------------------------------
// Pass 1 (MFMA): ScT[e][d] = sum_j v[j][e]*(exd_j k[j][d]); z[d] likewise.
// Transposed LDS tiles use JSW write/read swizzle.
// ---------------------------------------------------------------------------
__global__ __launch_bounds__(256) void pass1_kernel(
    const ushort_t* __restrict__ Kp, const ushort_t* __restrict__ Vp,
    const float* __restrict__ logf,
    ushort_t* __restrict__ Schunk, float* __restrict__ zchunk,
    float* __restrict__ Dchunk)
{
    __shared__ __align__(16) char smem[18688];
    ushort_t* vsT = (ushort_t*)smem;            // [64][72]: row e, col j (JSW)
    ushort_t* kTd = (ushort_t*)(smem + 9216);   // [64][72]: row d, col j (JSW)
    float*    exd = (float*)(smem + 18432);     // [64]

    const int chunk = blockIdx.x;
    const int bh = blockIdx.y;
    const int b = bh >> 4, h = bh & 15;
    const int tid = threadIdx.x;
    const int wv = tid >> 6, ln = tid & 63;
    const int fr = ln & 15, q4 = ln >> 4;
    const size_t slot = (size_t)bh * NCHUNK + chunk;

    u16x8 vreg[2], kreg[2];
    #pragma unroll
    for (int it = 0; it < 2; ++it) {
        const int u = it*256 + tid;
        const int j = u >> 3, d8 = (u & 7) * 8;
        const size_t base = (size_t)((chunk*64 + j)*BATCH + b)*HID + h*HD + d8;
        vreg[it] = *(const u16x8*)(Vp + base);
        kreg[it] = *(const u16x8*)(Kp + base);
    }
    if (tid < 64) {
        float v = logf[(size_t)((chunk*64 + tid)*BATCH + b) * HEADS + h];
        #pragma unroll
        for (int off = 1; off < 64; off <<= 1) {
            float n = __shfl_up(v, off);
            if (tid >= off) v += n;
        }
        const float tot = __shfl(v, 63);
        exd[tid] = __expf(tot - v);
        if (tid == 63) Dchunk[slot] = __expf(tot);
    }
    __syncthreads();

    #pragma unroll
    for (int it = 0; it < 2; ++it) {
        const int u = it*256 + tid;
        const int j = u >> 3, d8 = (u & 7) * 8;
        const int js = j ^ ((u & 7) << 3);       // JSW(d8+i, j), (d8+i)>>3 == u&7
        const float ex = exd[j];
        #pragma unroll
        for (int i = 0; i < 8; ++i) {
            vsT[(d8+i)*72 + js] = vreg[it][i];
            kTd[(d8+i)*72 + js] = f2bf(bf2f(kreg[it][i]) * ex);
        }
    }
    __syncthreads();

    f32x4 acc[4];
    #pragma unroll
    for (int nt = 0; nt < 4; ++nt) acc[nt] = (f32x4){0.f,0.f,0.f,0.f};
    #pragma unroll
    for (int k0 = 0; k0 < 64; k0 += 32) {
        const int rA = wv*16 + fr;
        bf16x8 av = *(const bf16x8*)(vsT + rA*72 + JSW(rA, k0 + q4*8));
        #pragma unroll
        for (int nt = 0; nt < 4; ++nt) {
            const int rB = nt*16 + fr;
            bf16x8 bk = *(const bf16x8*)(kTd + rB*72 + JSW(rB, k0 + q4*8));
            acc[nt] = __builtin_amdgcn_mfma_f32_16x16x32_bf16(av, bk, acc[nt], 0, 0, 0);
        }
    }

    if (wv == 0) {
        u16x8 onesu;
        #pragma unroll
        for (int i = 0; i < 8; ++i) onesu[i] = 0x3F80;   // bf16 1.0
        const bf16x8 ones = *(const bf16x8*)&onesu;
        f32x4 zacc[4];
        #pragma unroll
        for (int nt = 0; nt < 4; ++nt) zacc[nt] = (f32x4){0.f,0.f,0.f,0.f};
        #pragma unroll
        for (int k0 = 0; k0 < 64; k0 += 32) {
            #pragma unroll
            for (int nt = 0; nt < 4; ++nt) {
                const int rB = nt*16 + fr;
                bf16x8 bk = *(const bf16x8*)(kTd + rB*72 + JSW(rB, k0 + q4*8));
                zacc[nt] = __builtin_amdgcn_mfma_f32_16x16x32_bf16(ones, bk, zacc[nt], 0, 0, 0);
            }
        }
        if (q4 == 0) {
            #pragma unroll
            for (int nt = 0; nt < 4; ++nt)
                zchunk[slot*64 + nt*16 + fr] = zacc[nt][0];
        }
    }

    ushort_t* sp = Schunk + slot * 4096;
    #pragma unroll
    for (int nt = 0; nt < 4; ++nt) {
        #pragma unroll
        for (int r = 0; r < 4; ++r) {
            const int e = wv*16 + q4*4 + r;
            sp[e*64 + nt*16 + fr] = f2bf(acc[nt][r]);
        }
    }
}

// ---------------------------------------------------------------------------
// Pass 2: sequential over 32 chunks; 512 blocks (8 slices per bh), 128 thr,
// 4 bf16/thread via u16x4 (8B/lane), depth-2 prefetch.
// ---------------------------------------------------------------------------
__global__ __launch_bounds__(128) void pass2_kernel(
    ushort_t* __restrict__ Schunk, float* __restrict__ zchunk,
    const float* __restrict__ Dchunk)
{
    __shared__ float Ds[NCHUNK];
    const int bh  = blockIdx.x >> 3;
    const int sl  = blockIdx.x & 7;
    const int tid = threadIdx.x;

    if (tid < NCHUNK) Ds[tid] = Dchunk[bh * NCHUNK + tid];

    float Sprev[4] = {0.f, 0.f, 0.f, 0.f};
    float zprev = 0.f;

    const size_t base  = (size_t)bh * NCHUNK * 4096 + sl * 512 + tid * 4;
    const size_t zbase = (size_t)bh * NCHUNK * 64;
    const bool doZ = (sl == 0) && (tid < 64);

    u16x4 b0 = *(const u16x4*)(Schunk + base);
    u16x4 b1 = *(const u16x4*)(Schunk + base + 4096);
    float z0v = 0.f, z1v = 0.f;
    if (doZ) {
        z0v = zchunk[zbase + tid];
        z1v = zchunk[zbase + 64 + tid];
    }
    __syncthreads();

    for (int c = 0; c < NCHUNK; ++c) {
        const float D = Ds[c];
        ushort_t* sp = Schunk + base + (size_t)c * 4096;
        u16x4 wout;
        #pragma unroll
        for (int i = 0; i < 4; ++i) {
            wout[i] = f2bf(Sprev[i]);
            Sprev[i] = D * Sprev[i] + bf2f(b0[i]);
        }
        *(u16x4*)sp = wout;
        b0 = b1;
        if (doZ) {
            zchunk[zbase + (size_t)c * 64 + tid] = zprev;
            zprev = D * zprev + z0v;
            z0v = z1v;
        }
        if (c + 2 < NCHUNK) {
            b1 = *(const u16x4*)(Schunk + base + (size_t)(c+2)*4096);
            if (doZ) z1v = zchunk[zbase + (size_t)(c+2)*64 + tid];
        }
    }
}

// ---------------------------------------------------------------------------
// Pass 3 (full-MFMA): per (bh, chunk) attention outputs -> bf16 AO.
// vsT transpose scatter uses JSW. S0 B-fragments prefetched to registers at
// kernel entry (round-8 win).
// ---------------------------------------------------------------------------
__global__ __launch_bounds__(256) void pass3_kernel(
    const ushort_t* __restrict__ Qp, const ushort_t* __restrict__ Kp,
    const ushort_t* __restrict__ Vp, const float* __restrict__ logf,
    const ushort_t* __restrict__ S0, const float* __restrict__ z0,
    ushort_t* __restrict__ AO)
{
    __shared__ __align__(16) char smem[28928];
    ushort_t* qs  = (ushort_t*)smem;               // [64][72] (t rows)
    ushort_t* ks  = (ushort_t*)(smem + 9216);      // [64][72] (j rows) phase A
    ushort_t* vsT = (ushort_t*)(smem + 9216);      // [64][72] (e rows, JSW) phase B
    ushort_t* psA = (ushort_t*)(smem + 18432);     // [64][72] P
    float* cc  = (float*)(smem + 27648);
    float* exT = (float*)(smem + 27904);
    float* qz  = (float*)(smem + 28160);
    float* den = (float*)(smem + 28416);
    float* zz  = (float*)(smem + 28672);

    const int chunk = blockIdx.x;
    const int bh = blockIdx.y;
    const int b = bh >> 4, h = bh & 15;
    const int tid = threadIdx.x;
    const int wv = tid >> 6, ln = tid & 63;
    const int fr = ln & 15, q4 = ln >> 4;
    const size_t slot = (size_t)bh * NCHUNK + chunk;

    // prefetch V rows into registers (scattered to LDS after B2)
    u16x8 vreg[2];
    #pragma unroll
    for (int it = 0; it < 2; ++it) {
        const int u = it*256 + tid;
        const int j = u >> 3, d8 = (u & 7) * 8;
        vreg[it] = *(const u16x8*)(Vp + (size_t)((chunk*64 + j)*BATCH + b)*HID + h*HD + d8);
    }
    // prefetch S0 B-fragments into registers (consumed after B3)
    bf16x8 s0r[4][2];
    {
        const ushort_t* S0p = S0 + slot * 4096;
        #pragma unroll
        for (int nt = 0; nt < 4; ++nt)
            #pragma unroll
            for (int kk = 0; kk < 2; ++kk)
                s0r[nt][kk] = *(const bf16x8*)(S0p + (nt*16 + fr)*64 + kk*32 + q4*8);
    }

    if (tid < 64) {
        zz[tid] = z0[slot * 64 + tid];
        float v = logf[(size_t)((chunk*64 + tid)*BATCH + b) * HEADS + h];
        #pragma unroll
        for (int off = 1; off < 64; off <<= 1) {
            float n = __shfl_up(v, off);
            if (tid >= off) v += n;
        }
        cc[tid]  = v;
        exT[tid] = __expf(v);
    }
    #pragma unroll
    for (int it = 0; it < 2; ++it) {
        const int u = it*256 + tid;
        const int r = u >> 3, c8 = (u & 7) * 8;
        const size_t goff = (size_t)((chunk*64 + r)*BATCH + b) * HID + h*HD + c8;
        *(u16x8*)(qs + r*72 + c8) = *(const u16x8*)(Qp + goff);
        *(u16x8*)(ks + r*72 + c8) = *(const u16x8*)(Kp + goff);
    }
    __syncthreads();   // B1

    f32x4 pacc[4];
    #pragma unroll
    for (int nt = 0; nt < 4; ++nt) pacc[nt] = (f32x4){0.f,0.f,0.f,0.f};
    #pragma unroll
    for (int k0 = 0; k0 < 64; k0 += 32) {
        bf16x8 af = *(const bf16x8*)(qs + (wv*16 + fr)*72 + k0 + q4*8);
        #pragma unroll
        for (int nt = 0; nt < 4; ++nt) {
            bf16x8 bfr = *(const bf16x8*)(ks + (nt*16 + fr)*72 + k0 + q4*8);
            pacc[nt] = __builtin_amdgcn_mfma_f32_16x16x32_bf16(af, bfr, pacc[nt], 0, 0, 0);
        }
    }
    // qz[t], t = wv*16+fr, all waves: 16-elem partials over d + xor-reduce
    {
        const int t = wv*16 + fr;
        const int d0 = q4 * 16;
        float s = 0.f;
        #pragma unroll
        for (int i = 0; i < 16; ++i)
            s += bf2f(qs[t*72 + d0 + i]) * zz[d0 + i];
        s += __shfl_xor(s, 16);
        s += __shfl_xor(s, 32);
        if (q4 == 0) qz[t] = s;
    }
    __syncthreads();   // B2 — ks reads done; vsT may overwrite

    #pragma unroll
    for (int it = 0; it < 2; ++it) {
        const int u = it*256 + tid;
        const int j = u >> 3, d8 = (u & 7) * 8;
        const int js = j ^ ((u & 7) << 3);       // JSW(d8+i, j)
        #pragma unroll
        for (int i = 0; i < 8; ++i)
            vsT[(d8+i)*72 + js] = vreg[it][i];
    }
    {
        float rs[4] = {0.f, 0.f, 0.f, 0.f};
        float cct[4];
        #pragma unroll
        for (int r = 0; r < 4; ++r) cct[r] = cc[wv*16 + q4*4 + r];
        #pragma unroll
        for (int nt = 0; nt < 4; ++nt) {
            const int j = nt*16 + fr;
            const float ccj = cc[j];
            #pragma unroll
            for (int r = 0; r < 4; ++r) {
                const int t = wv*16 + q4*4 + r;
                float p = (j <= t) ? pacc[nt][r] * __expf(cct[r] - ccj) : 0.f;
                rs[r] += p;
                psA[t*72 + j] = f2bf(p);
            }
        }
        #pragma unroll
        for (int m = 1; m < 16; m <<= 1) {
            #pragma unroll
            for (int r = 0; r < 4; ++r) rs[r] += __shfl_xor(rs[r], m);
        }
        if (fr == 0) {
            #pragma unroll
            for (int r = 0; r < 4; ++r) {
                const int t = wv*16 + q4*4 + r;
                den[t] = rs[r] + exT[t] * qz[t] + 1e-6f;
            }
        }
    }
    __syncthreads();   // B3

    f32x4 oacc[4], oacc2[4];
    #pragma unroll
    for (int nt = 0; nt < 4; ++nt) {
        oacc[nt]  = (f32x4){0.f,0.f,0.f,0.f};
        oacc2[nt] = (f32x4){0.f,0.f,0.f,0.f};
    }
    #pragma unroll
    for (int kk = 0; kk < 2; ++kk) {
        const int k8 = kk*32 + q4*8;
        bf16x8 ap = *(const bf16x8*)(psA + (wv*16 + fr)*72 + k8);
        bf16x8 aq = *(const bf16x8*)(qs  + (wv*16 + fr)*72 + k8);
        #pragma unroll
        for (int nt = 0; nt < 4; ++nt) {
            const int rV = nt*16 + fr;
            bf16x8 bv = *(const bf16x8*)(vsT + rV*72 + JSW(rV, k8));
            oacc[nt] = __builtin_amdgcn_mfma_f32_16x16x32_bf16(ap, bv, oacc[nt], 0, 0, 0);
            oacc2[nt] = __builtin_amdgcn_mfma_f32_16x16x32_bf16(aq, s0r[nt][kk], oacc2[nt], 0, 0, 0);
        }
    }
    #pragma unroll
    for (int nt = 0; nt < 4; ++nt) {
        const int e = nt*16 + fr;
        #pragma unroll
        for (int r = 0; r < 4; ++r) {
            const int t = wv*16 + q4*4 + r;
            const float v = (oacc[nt][r] + exT[t] * oacc2[nt][r]) / den[t];
            AO[(size_t)((chunk*64 + t)*BATCH + b) * HID + h*HD + e] = f2bf(v);
        }
    }
}

// ---------------------------------------------------------------------------
extern "C" void kernel_launch(void* const* d_in, const int* in_sizes, int n_in,
                              void* d_out, int out_size, void* d_ws, size_t ws_size,
                              hipStream_t stream) {
    const float* X  = (const float*)d_in[0];
    const float* Wq = (const float*)d_in[1];
    const float* bq = (const float*)d_in[2];
    const float* Wk = (const float*)d_in[3];
    const float* bk = (const float*)d_in[4];
    const float* Wv = (const float*)d_in[5];
    const float* bv = (const float*)d_in[6];
    const float* Wf = (const float*)d_in[7];
    const float* bf = (const float*)d_in[8];
    const float* Wo = (const float*)d_in[9];
    const float* bo = (const float*)d_in[10];

    float* out = (float*)d_out;
    const size_t OUT_SLOT = (size_t)SB * HID;

    char* ws = (char*)d_ws;
    ushort_t* wsXb   = (ushort_t*)ws;                       // SB*HID bf16 (X, later AO)
    ushort_t* wsWstk = wsXb + (size_t)SB * HID;             // NSTK*HID bf16
    ushort_t* wsWob  = wsWstk + (size_t)NSTK * HID;         // HID*HID bf16
    ushort_t* wsQ    = wsWob + (size_t)HID * HID;           // [row][col]
    ushort_t* wsK    = wsQ + (size_t)SB * HID;              // [row][col]
    ushort_t* wsV    = wsK + (size_t)SB * HID;              // [row][col]
    float* wsBstk = (float*)(wsV + (size_t)SB * HID);       // NSTK fp32
    float* wsLogf = wsBstk + NSTK;                          // SB*HEADS fp32
    ushort_t* wsS  = (ushort_t*)(wsLogf + (size_t)SB * HEADS); // bf16 S^T chunks -> S0^T
    float* wsZ    = (float*)(wsS + (size_t)BH * NCHUNK * HD * HD);
    float* wsD    = wsZ + (size_t)BH * NCHUNK * HD;

    // zero slot 1 (second output) via memset node
    hipMemsetAsync(out + OUT_SLOT, 0, OUT_SLOT * sizeof(float), stream);

    prep_kernel<<<(NTOT + 255)/256, 256, 0, stream>>>(
        X, Wq, Wk, Wv, Wf, Wo, bq, bk, bv, bf,
        wsXb, wsWstk, wsWob, wsBstk);

    dim3 qgrid(SB/128, NSTK/128);   // x = row (64), y = col (25)
    qkvf_gemm<<<qgrid, 512, 0, stream>>>(
        wsXb, wsWstk, wsBstk, wsQ, wsK, wsV,
        out + 2*OUT_SLOT, wsLogf);

    dim3 sgrid(NCHUNK, BH);
    pass1_kernel<<<sgrid, 256, 0, stream>>>(wsK, wsV, wsLogf, wsS, wsZ, wsD);
    pass2_kernel<<<BH*8, 128, 0, stream>>>(wsS, wsZ, wsD);
    pass3_kernel<<<sgrid, 256, 0, stream>>>(wsQ, wsK, wsV, wsLogf, wsS, wsZ, wsXb);

    dim3 ogrid(SB/128, HID/128);    // x = row (64), y = col (8)
    gemm_out<<<ogrid, 512, 0, stream>>>(wsXb, wsWob, bo, out);
}